// Round 9
// baseline (204.612 us; speedup 1.0000x reference)
//
#include <hip/hip_runtime.h>
#include <hip/hip_bf16.h>

#define NNODES 8192
#define DIN 512
#define HD1 256
#define LATD 128
#define CAP 128   // bucket capacity; P(deg>128) < 1e-18 for Binom(262144, 1/8192)

typedef __attribute__((ext_vector_type(4))) float f32x4;
typedef __attribute__((ext_vector_type(8))) short short8;

__device__ __forceinline__ float bf2f(uint u){
  union { uint i; float f; } v; v.i = u << 16; return v.f;
}
__device__ __forceinline__ ushort f2bf(float f){
  union { float f; uint i; } v; v.f = f;
  uint i = v.i;
  i += 0x7FFFu + ((i >> 16) & 1u);
  return (ushort)(i >> 16);
}

// ---------------- gemm1 body: h1 = bf16(x) @ bf16(W1), 64x256 tile ----------------

__device__ __forceinline__ void gemm1_body(const float* __restrict__ x,
    const float* __restrict__ W1, ushort* __restrict__ h1, int bx)
{
  __shared__ ushort Al[64][40];
  __shared__ ushort Bl[256][40];   // transposed: Bl[n][k]
  const int m0 = bx * 64;
  const int t = threadIdx.x;
  const int w = t >> 6, l = t & 63, lr = l & 15, lk = l >> 4;
  const int wm = (w >> 2) * 32, wn = (w & 3) * 64;
  f32x4 acc[2][4] = {};
  for (int kt = 0; kt < DIN / 32; ++kt){
    {
      const int row = t >> 3, ch = (t & 7) * 4;
      const float4 v = *(const float4*)(x + (size_t)(m0 + row) * DIN + kt * 32 + ch);
      uint2 wv;
      wv.x = (uint)f2bf(v.x) | ((uint)f2bf(v.y) << 16);
      wv.y = (uint)f2bf(v.z) | ((uint)f2bf(v.w) << 16);
      *(uint2*)(&Al[row][ch]) = wv;
      const int kk = t >> 4, nn = (t & 15) * 16;
      const float* bp = W1 + (size_t)(kt * 32 + kk) * HD1 + nn;
      #pragma unroll
      for (int i = 0; i < 4; ++i){
        float4 bv = *(const float4*)(bp + i * 4);
        Bl[nn + i * 4 + 0][kk] = f2bf(bv.x); Bl[nn + i * 4 + 1][kk] = f2bf(bv.y);
        Bl[nn + i * 4 + 2][kk] = f2bf(bv.z); Bl[nn + i * 4 + 3][kk] = f2bf(bv.w);
      }
    }
    __syncthreads();
    short8 a0 = *(const short8*)(&Al[wm + lr][lk * 8]);
    short8 a1 = *(const short8*)(&Al[wm + 16 + lr][lk * 8]);
    #pragma unroll
    for (int ni = 0; ni < 4; ++ni){
      short8 b = *(const short8*)(&Bl[wn + ni * 16 + lr][lk * 8]);
      acc[0][ni] = __builtin_amdgcn_mfma_f32_16x16x32_bf16(a0, b, acc[0][ni], 0, 0, 0);
      acc[1][ni] = __builtin_amdgcn_mfma_f32_16x16x32_bf16(a1, b, acc[1][ni], 0, 0, 0);
    }
    __syncthreads();
  }
  #pragma unroll
  for (int mi = 0; mi < 2; ++mi){
    #pragma unroll
    for (int ni = 0; ni < 4; ++ni){
      const int row = m0 + wm + mi * 16 + lk * 4;
      const int col = wn + ni * 16 + lr;
      #pragma unroll
      for (int r = 0; r < 4; ++r)
        h1[(size_t)(row + r) * HD1 + col] = f2bf(acc[mi][ni][r]);
    }
  }
}

// fused: blocks [0, nbF): fill csr buckets; blocks [nbF, nbF+128): gemm1 tiles
__global__ __launch_bounds__(512) void k_fill_gemm1(const int* __restrict__ erow,
    const int* __restrict__ ecol, int E, int nbF,
    int* __restrict__ cursor, int* __restrict__ csr,
    const float* __restrict__ x, const float* __restrict__ W1, ushort* __restrict__ h1)
{
  if ((int)blockIdx.x < nbF){
    int e = blockIdx.x * 512 + threadIdx.x;
    if (e < E){
      int r = erow[e], c = ecol[e];
      int pos = atomicAdd(&cursor[c], 1);
      if (pos < CAP) csr[(size_t)c * CAP + pos] = r;
    }
    return;
  }
  gemm1_body(x, W1, h1, blockIdx.x - nbF);
}

// PROBE: pure gemm1 (idempotent re-run; marginal dur = gemm1 cost)
__global__ __launch_bounds__(512) void k_gemm1_probe(const float* __restrict__ x,
    const float* __restrict__ W1, ushort* __restrict__ h1)
{
  gemm1_body(x, W1, h1, blockIdx.x);
}

// ---------------- GEMM body (64x64 tile, 4 waves) for gemm2 / mulv ----------------

__device__ __forceinline__ void gemm_body(const ushort* __restrict__ A,
    const float* __restrict__ B, ushort* __restrict__ Cb,
    int n0, int m0, int N, int K)
{
  __shared__ ushort Al[64][40];
  __shared__ ushort Bl[64][40];
  const int t = threadIdx.x;
  const int wid = t >> 6, l = t & 63, lr = l & 15, lk = l >> 4;
  const int wm = (wid >> 1) * 32, wn = (wid & 1) * 32;
  f32x4 acc[2][2] = {};
  const int nkt = K >> 5;
  for (int kt = 0; kt < nkt; ++kt){
    {
      const int row = t >> 2, ch = t & 3;
      *(short8*)(&Al[row][ch * 8]) =
        *(const short8*)(A + (size_t)(m0 + row) * K + kt * 32 + ch * 8);
      const int kk = t >> 3, nn = (t & 7) * 8;
      const float* bp = B + (size_t)(kt * 32 + kk) * N + n0 + nn;
      float4 v0 = *(const float4*)bp;
      float4 v1 = *(const float4*)(bp + 4);
      Bl[nn + 0][kk] = f2bf(v0.x); Bl[nn + 1][kk] = f2bf(v0.y);
      Bl[nn + 2][kk] = f2bf(v0.z); Bl[nn + 3][kk] = f2bf(v0.w);
      Bl[nn + 4][kk] = f2bf(v1.x); Bl[nn + 5][kk] = f2bf(v1.y);
      Bl[nn + 6][kk] = f2bf(v1.z); Bl[nn + 7][kk] = f2bf(v1.w);
    }
    __syncthreads();
    short8 a0 = *(const short8*)(&Al[wm + lr][lk * 8]);
    short8 a1 = *(const short8*)(&Al[wm + 16 + lr][lk * 8]);
    short8 b0 = *(const short8*)(&Bl[wn + lr][lk * 8]);
    short8 b1 = *(const short8*)(&Bl[wn + 16 + lr][lk * 8]);
    acc[0][0] = __builtin_amdgcn_mfma_f32_16x16x32_bf16(a0, b0, acc[0][0], 0, 0, 0);
    acc[0][1] = __builtin_amdgcn_mfma_f32_16x16x32_bf16(a0, b1, acc[0][1], 0, 0, 0);
    acc[1][0] = __builtin_amdgcn_mfma_f32_16x16x32_bf16(a1, b0, acc[1][0], 0, 0, 0);
    acc[1][1] = __builtin_amdgcn_mfma_f32_16x16x32_bf16(a1, b1, acc[1][1], 0, 0, 0);
    __syncthreads();
  }
  #pragma unroll
  for (int mi = 0; mi < 2; ++mi){
    #pragma unroll
    for (int ni = 0; ni < 2; ++ni){
      const int row = m0 + wm + mi * 16 + lk * 4;
      const int col = n0 + wn + ni * 16 + lr;
      #pragma unroll
      for (int r = 0; r < 4; ++r)
        Cb[(size_t)(row + r) * N + col] = f2bf(acc[mi][ni][r]);
    }
  }
}

__global__ __launch_bounds__(256) void gemm2_kernel(const ushort* __restrict__ A,
    const float* __restrict__ B, ushort* __restrict__ Cb)
{
  gemm_body(A, B, Cb, blockIdx.x * 64, blockIdx.y * 64, LATD, HD1);
}

// ---------------- fused mu/logvar GEMM ----------------

__global__ __launch_bounds__(256) void gemm_mulv(const ushort* __restrict__ A,
    const float* __restrict__ Wmu, const float* __restrict__ bmu,
    const float* __restrict__ Wlv, const float* __restrict__ blv,
    float* __restrict__ mu, ushort* __restrict__ mu_bf, float* __restrict__ lv)
{
  __shared__ ushort Al[64][40];
  __shared__ ushort Bl[64][40];
  const int t = threadIdx.x;
  const int gn0 = blockIdx.x * 64, m0 = blockIdx.y * 64;
  const bool is_mu = gn0 < LATD;
  const float* B = is_mu ? Wmu : Wlv;
  const float* bias = is_mu ? bmu : blv;
  const int n0 = gn0 & (LATD - 1);
  const int wid = t >> 6, l = t & 63, lr = l & 15, lk = l >> 4;
  const int wm = (wid >> 1) * 32, wn = (wid & 1) * 32;
  f32x4 acc[2][2] = {};
  for (int kt = 0; kt < LATD / 32; ++kt){
    {
      const int row = t >> 2, ch = t & 3;
      *(short8*)(&Al[row][ch * 8]) =
        *(const short8*)(A + (size_t)(m0 + row) * LATD + kt * 32 + ch * 8);
      const int kk = t >> 3, nn = (t & 7) * 8;
      const float* bp = B + (size_t)(kt * 32 + kk) * LATD + n0 + nn;
      float4 v0 = *(const float4*)bp;
      float4 v1 = *(const float4*)(bp + 4);
      Bl[nn + 0][kk] = f2bf(v0.x); Bl[nn + 1][kk] = f2bf(v0.y);
      Bl[nn + 2][kk] = f2bf(v0.z); Bl[nn + 3][kk] = f2bf(v0.w);
      Bl[nn + 4][kk] = f2bf(v1.x); Bl[nn + 5][kk] = f2bf(v1.y);
      Bl[nn + 6][kk] = f2bf(v1.z); Bl[nn + 7][kk] = f2bf(v1.w);
    }
    __syncthreads();
    short8 a0 = *(const short8*)(&Al[wm + lr][lk * 8]);
    short8 a1 = *(const short8*)(&Al[wm + 16 + lr][lk * 8]);
    short8 b0 = *(const short8*)(&Bl[wn + lr][lk * 8]);
    short8 b1 = *(const short8*)(&Bl[wn + 16 + lr][lk * 8]);
    acc[0][0] = __builtin_amdgcn_mfma_f32_16x16x32_bf16(a0, b0, acc[0][0], 0, 0, 0);
    acc[0][1] = __builtin_amdgcn_mfma_f32_16x16x32_bf16(a0, b1, acc[0][1], 0, 0, 0);
    acc[1][0] = __builtin_amdgcn_mfma_f32_16x16x32_bf16(a1, b0, acc[1][0], 0, 0, 0);
    acc[1][1] = __builtin_amdgcn_mfma_f32_16x16x32_bf16(a1, b1, acc[1][1], 0, 0, 0);
    __syncthreads();
  }
  #pragma unroll
  for (int mi = 0; mi < 2; ++mi){
    #pragma unroll
    for (int ni = 0; ni < 2; ++ni){
      const int row = m0 + wm + mi * 16 + lk * 4;
      const int col = n0 + wn + ni * 16 + lr;
      float bb = bias[col];
      #pragma unroll
      for (int r = 0; r < 4; ++r){
        float v = acc[mi][ni][r] + bb;
        if (is_mu){
          mu[(size_t)(row + r) * LATD + col] = v;
          mu_bf[(size_t)(row + r) * LATD + col] = f2bf(v);
        } else {
          lv[(size_t)(row + r) * LATD + col] = v;
        }
      }
    }
  }
}

// ---------------- aggregation (bucket CSR, on-the-fly dis) ----------------

template<int F, bool RELU>
__global__ __launch_bounds__(256) void agg_kernel(const ushort* __restrict__ h,
    const float* __restrict__ bias, const int* __restrict__ cnt,
    const int* __restrict__ csr, ushort* __restrict__ out)
{
  constexpr int LPE = F / 8;
  constexpr int EPI = 64 / LPE;
  __shared__ int2 meta[4][64];
  const int w = threadIdx.x >> 6, l = threadIdx.x & 63;
  const int v = blockIdx.x * 4 + w;
  const int deg = min(cnt[v], CAP);
  const float dv = rsqrtf((float)(deg + 2));   // +2 self-loops (forward + gcn_norm)
  const int sub = l / LPE;
  const int eb = (l % LPE) * 8;
  float acc[8] = {0.f, 0.f, 0.f, 0.f, 0.f, 0.f, 0.f, 0.f};

  const int beg = v * CAP, end = beg + deg;
  for (int base = beg; base < end; base += 64){
    const int cc = min(64, end - base);
    int idx = 0; float nr = 0.f;
    if (base + l < end){
      idx = csr[base + l];
      nr = rsqrtf((float)(min(cnt[idx], CAP) + 2)) * dv;
    }
    int2 m; m.x = idx; m.y = __float_as_int(nr);
    meta[w][l] = m;
    asm volatile("s_waitcnt lgkmcnt(0)" ::: "memory");
    const int nIt = (cc + EPI - 1) / EPI;
    for (int it = 0; it < nIt; ++it){
      int2 mm = meta[w][it * EPI + sub];
      const float nrr = __int_as_float(mm.y);
      const uint4 r = *(const uint4*)(h + (size_t)mm.x * F + eb);
      acc[0] += nrr * bf2f(r.x & 0xffff); acc[1] += nrr * bf2f(r.x >> 16);
      acc[2] += nrr * bf2f(r.y & 0xffff); acc[3] += nrr * bf2f(r.y >> 16);
      acc[4] += nrr * bf2f(r.z & 0xffff); acc[5] += nrr * bf2f(r.z >> 16);
      acc[6] += nrr * bf2f(r.w & 0xffff); acc[7] += nrr * bf2f(r.w >> 16);
    }
    asm volatile("s_waitcnt lgkmcnt(0)" ::: "memory");
  }
  #pragma unroll
  for (int off = LPE; off < 64; off <<= 1){
    #pragma unroll
    for (int j = 0; j < 8; ++j) acc[j] += __shfl_xor(acc[j], off);
  }
  if (l < LPE){
    const float ss = 2.f * dv * dv;
    const uint4 r = *(const uint4*)(h + (size_t)v * F + eb);
    acc[0] += ss * bf2f(r.x & 0xffff); acc[1] += ss * bf2f(r.x >> 16);
    acc[2] += ss * bf2f(r.y & 0xffff); acc[3] += ss * bf2f(r.y >> 16);
    acc[4] += ss * bf2f(r.z & 0xffff); acc[5] += ss * bf2f(r.z >> 16);
    acc[6] += ss * bf2f(r.w & 0xffff); acc[7] += ss * bf2f(r.w >> 16);
    float4 b0 = *(const float4*)(bias + eb);
    float4 b1 = *(const float4*)(bias + eb + 4);
    acc[0] += b0.x; acc[1] += b0.y; acc[2] += b0.z; acc[3] += b0.w;
    acc[4] += b1.x; acc[5] += b1.y; acc[6] += b1.z; acc[7] += b1.w;
    if (RELU){
      #pragma unroll
      for (int j = 0; j < 8; ++j) acc[j] = fmaxf(acc[j], 0.f);
    }
    uint4 o;
    o.x = (uint)f2bf(acc[0]) | ((uint)f2bf(acc[1]) << 16);
    o.y = (uint)f2bf(acc[2]) | ((uint)f2bf(acc[3]) << 16);
    o.z = (uint)f2bf(acc[4]) | ((uint)f2bf(acc[5]) << 16);
    o.w = (uint)f2bf(acc[6]) | ((uint)f2bf(acc[7]) << 16);
    *(uint4*)(out + (size_t)v * F + eb) = o;
  }
}

// ---------------- adj = sigmoid(mu @ mu^T), 128x128 tiles, f32 out ----------------

__global__ __launch_bounds__(512) void gemm5_kernel(const ushort* __restrict__ mu,
                                                    float* __restrict__ adj)
{
  __shared__ char lds[65536];
  const int t = threadIdx.x;
  const int bj = blockIdx.x, bi = blockIdx.y;
  {
    const int row = t >> 2, ch = t & 3;
    const char* srcA = (const char*)(mu + (size_t)(bi * 128 + row) * LATD);
    const char* srcB = (const char*)(mu + (size_t)(bj * 128 + row) * LATD);
    char* dA = lds + row * 256;
    char* dB = lds + 32768 + row * 256;
    #pragma unroll
    for (int i = 0; i < 4; ++i){
      const int kb = ch * 64 + i * 16;
      const int sk = kb ^ ((row & 7) << 4);
      *(short8*)(dA + sk) = *(const short8*)(srcA + kb);
      *(short8*)(dB + sk) = *(const short8*)(srcB + kb);
    }
  }
  __syncthreads();
  const int wid = t >> 6, l = t & 63, lr = l & 15, lk = l >> 4;
  const int wm = (wid >> 2) * 64, wn = (wid & 3) * 32;
  f32x4 acc[4][2] = {};
  #pragma unroll
  for (int ks = 0; ks < 4; ++ks){
    short8 a[4], b[2];
    const int kb = ks * 64 + lk * 16;
    #pragma unroll
    for (int mi = 0; mi < 4; ++mi){
      const int r = wm + mi * 16 + lr;
      a[mi] = *(const short8*)(lds + r * 256 + (kb ^ ((r & 7) << 4)));
    }
    #pragma unroll
    for (int ni = 0; ni < 2; ++ni){
      const int r = wn + ni * 16 + lr;
      b[ni] = *(const short8*)(lds + 32768 + r * 256 + (kb ^ ((r & 7) << 4)));
    }
    #pragma unroll
    for (int mi = 0; mi < 4; ++mi)
      #pragma unroll
      for (int ni = 0; ni < 2; ++ni)
        acc[mi][ni] = __builtin_amdgcn_mfma_f32_16x16x32_bf16(a[mi], b[ni], acc[mi][ni], 0, 0, 0);
  }
  float* orow = adj + (size_t)(bi * 128 + wm + lk * 4) * NNODES + bj * 128 + wn + lr;
  #pragma unroll
  for (int mi = 0; mi < 4; ++mi){
    #pragma unroll
    for (int ni = 0; ni < 2; ++ni){
      #pragma unroll
      for (int r = 0; r < 4; ++r){
        const float x = acc[mi][ni][r];
        orow[(size_t)(mi * 16 + r) * NNODES + ni * 16] = 1.f / (1.f + __expf(-x));
      }
    }
  }
}

// ---------------- launch ----------------

extern "C" void kernel_launch(void* const* d_in, const int* in_sizes, int n_in,
                              void* d_out, int out_size, void* d_ws, size_t ws_size,
                              hipStream_t stream)
{
  const float* x    = (const float*)d_in[0];
  const int*   ei   = (const int*)d_in[1];
  const float* W1   = (const float*)d_in[2];
  const float* b1   = (const float*)d_in[3];
  const float* W2   = (const float*)d_in[4];
  const float* b2   = (const float*)d_in[5];
  const float* Wmu  = (const float*)d_in[6];
  const float* bmu  = (const float*)d_in[7];
  const float* Wlv  = (const float*)d_in[8];
  const float* blv  = (const float*)d_in[9];
  const int E = in_sizes[1] / 2;
  const int* erow = ei;
  const int* ecol = ei + E;

  char* ws = (char*)d_ws;
  int*    cnt   = (int*)(ws);                  // 32KB (cursor, becomes degree)
  int*    csr   = (int*)(ws + 1048576);        // 4MB buckets
  ushort* h1    = (ushort*)(ws + 8388608);     // 4MB
  ushort* z1    = (ushort*)(ws + 12582912);    // 4MB
  ushort* h2    = (ushort*)(ws + 16777216);    // 2MB
  ushort* z2    = (ushort*)(ws + 18874368);    // 2MB
  ushort* mu_bf = (ushort*)(ws + 20971520);    // 2MB

  float* adj = (float*)d_out;
  float* mu  = adj + (size_t)NNODES * NNODES;
  float* lv  = mu + (size_t)NNODES * LATD;

  const int nbF = (E + 511) / 512;

  hipMemsetAsync(cnt, 0, 32768, stream);
  // fused: bucket CSR fill + gemm1
  k_fill_gemm1<<<nbF + NNODES / 64, 512, 0, stream>>>(erow, ecol, E, nbF, cnt, csr, x, W1, h1);
  // PROBE: pure gemm1 re-run (idempotent)
  k_gemm1_probe<<<NNODES / 64, 512, 0, stream>>>(x, W1, h1);
  // z1 = relu(agg(h1) + b1)
  agg_kernel<HD1, true><<<NNODES / 4, 256, 0, stream>>>(h1, b1, cnt, csr, z1);
  // h2 = z1 @ W2 — launched TWICE (idempotent probe)
  gemm2_kernel<<<dim3(LATD / 64, NNODES / 64), 256, 0, stream>>>(z1, W2, h2);
  gemm2_kernel<<<dim3(LATD / 64, NNODES / 64), 256, 0, stream>>>(z1, W2, h2);
  // z2 = agg(h2) + b2
  agg_kernel<LATD, false><<<NNODES / 4, 256, 0, stream>>>(h2, b2, cnt, csr, z2);
  // mu / logvar — launched TWICE (idempotent probe)
  gemm_mulv<<<dim3(2 * LATD / 64, NNODES / 64), 256, 0, stream>>>(z2, Wmu, bmu, Wlv, blv, mu, mu_bf, lv);
  gemm_mulv<<<dim3(2 * LATD / 64, NNODES / 64), 256, 0, stream>>>(z2, Wmu, bmu, Wlv, blv, mu, mu_bf, lv);
  // adj = sigmoid(mu @ mu^T)
  gemm5_kernel<<<dim3(NNODES / 128, NNODES / 128), 512, 0, stream>>>(mu_bf, adj);
}

// Round 10
// 129.162 us; speedup vs baseline: 1.5841x; 1.5841x over previous
//
#include <hip/hip_runtime.h>
#include <hip/hip_bf16.h>

#define NNODES 8192
#define DIN 512
#define HD1 256
#define LATD 128
#define CAP 128   // bucket capacity; P(deg>128) < 1e-18 for Binom(262144, 1/8192)

typedef __attribute__((ext_vector_type(4))) float f32x4;
typedef __attribute__((ext_vector_type(8))) short short8;

__device__ __forceinline__ float bf2f(uint u){
  union { uint i; float f; } v; v.i = u << 16; return v.f;
}
__device__ __forceinline__ ushort f2bf(float f){
  union { float f; uint i; } v; v.f = f;
  uint i = v.i;
  i += 0x7FFFu + ((i >> 16) & 1u);
  return (ushort)(i >> 16);
}

// ---------------- k_init: zero cnt + convert weights to bf16 (once) ----------------
// Wcb = [Wmu | Wlv] concatenated along N (128 x 256).

__global__ __launch_bounds__(256) void k_init(const float* __restrict__ W1,
    const float* __restrict__ W2, const float* __restrict__ Wmu,
    const float* __restrict__ Wlv, int* __restrict__ cnt,
    ushort* __restrict__ W1b, ushort* __restrict__ W2b, ushort* __restrict__ Wcb)
{
  const int stride = gridDim.x * 256;
  const int i = blockIdx.x * 256 + threadIdx.x;
  if (i < NNODES) cnt[i] = 0;
  for (int j = i; j < DIN * HD1; j += stride) W1b[j] = f2bf(W1[j]);
  for (int j = i; j < HD1 * LATD; j += stride) W2b[j] = f2bf(W2[j]);
  for (int j = i; j < LATD * 2 * LATD; j += stride){
    const int k = j >> 8, n = j & 255;
    Wcb[j] = f2bf(n < LATD ? Wmu[k * LATD + n] : Wlv[k * LATD + n - LATD]);
  }
}

// ---------------- fused: bucket CSR fill + gemm1 (64x64 tiles, bf16 B) ----------------

__global__ __launch_bounds__(256) void k_fill_gemm1(const int* __restrict__ erow,
    const int* __restrict__ ecol, int E, int nbF,
    int* __restrict__ cursor, int* __restrict__ csr,
    const float* __restrict__ x, const ushort* __restrict__ W1b, ushort* __restrict__ h1)
{
  if ((int)blockIdx.x < nbF){
    int e = blockIdx.x * 256 + threadIdx.x;
    if (e < E){
      int r = erow[e], c = ecol[e];
      int pos = atomicAdd(&cursor[c], 1);
      if (pos < CAP) csr[(size_t)c * CAP + pos] = r;
    }
    return;
  }
  const int bx = blockIdx.x - nbF;
  const int n0 = (bx & 3) * 64, m0 = (bx >> 2) * 64;
  __shared__ ushort Al[64][40];
  __shared__ ushort Bl[64][40];   // transposed: Bl[n][k]
  const int t = threadIdx.x, w = t >> 6, l = t & 63, lr = l & 15, lk = l >> 4;
  const int wm = (w >> 1) * 32, wn = (w & 1) * 32;
  f32x4 acc[2][2] = {};
  for (int kt = 0; kt < DIN / 32; ++kt){
    {
      const int row = t >> 2, ch = t & 3;
      const float* ap = x + (size_t)(m0 + row) * DIN + kt * 32 + ch * 8;
      float4 v0 = *(const float4*)ap;
      float4 v1 = *(const float4*)(ap + 4);
      ushort* d = &Al[row][ch * 8];
      d[0] = f2bf(v0.x); d[1] = f2bf(v0.y); d[2] = f2bf(v0.z); d[3] = f2bf(v0.w);
      d[4] = f2bf(v1.x); d[5] = f2bf(v1.y); d[6] = f2bf(v1.z); d[7] = f2bf(v1.w);
      const int kk = t >> 3, nn = (t & 7) * 8;
      short8 bv = *(const short8*)(W1b + (size_t)(kt * 32 + kk) * HD1 + n0 + nn);
      #pragma unroll
      for (int i = 0; i < 8; ++i) Bl[nn + i][kk] = ((ushort*)&bv)[i];
    }
    __syncthreads();
    short8 a0 = *(const short8*)(&Al[wm + lr][lk * 8]);
    short8 a1 = *(const short8*)(&Al[wm + 16 + lr][lk * 8]);
    short8 b0 = *(const short8*)(&Bl[wn + lr][lk * 8]);
    short8 b1 = *(const short8*)(&Bl[wn + 16 + lr][lk * 8]);
    acc[0][0] = __builtin_amdgcn_mfma_f32_16x16x32_bf16(a0, b0, acc[0][0], 0, 0, 0);
    acc[0][1] = __builtin_amdgcn_mfma_f32_16x16x32_bf16(a0, b1, acc[0][1], 0, 0, 0);
    acc[1][0] = __builtin_amdgcn_mfma_f32_16x16x32_bf16(a1, b0, acc[1][0], 0, 0, 0);
    acc[1][1] = __builtin_amdgcn_mfma_f32_16x16x32_bf16(a1, b1, acc[1][1], 0, 0, 0);
    __syncthreads();
  }
  #pragma unroll
  for (int mi = 0; mi < 2; ++mi){
    #pragma unroll
    for (int ni = 0; ni < 2; ++ni){
      const int row = m0 + wm + mi * 16 + lk * 4;
      const int col = n0 + wn + ni * 16 + lr;
      #pragma unroll
      for (int r = 0; r < 4; ++r)
        h1[(size_t)(row + r) * HD1 + col] = f2bf(acc[mi][ni][r]);
    }
  }
}

// ---------------- gemm2: h2 = z1 @ W2b, 32x64 tiles (512 blocks) ----------------

__global__ __launch_bounds__(256) void gemm2_kernel(const ushort* __restrict__ A,
    const ushort* __restrict__ Bb, ushort* __restrict__ Cb)
{
  __shared__ ushort Al[32][40];
  __shared__ ushort Bl[64][40];
  const int t = threadIdx.x, w = t >> 6, l = t & 63, lr = l & 15, lk = l >> 4;
  const int m0 = blockIdx.y * 32, n0 = blockIdx.x * 64;
  const int wm = (w >> 1) * 16, wn = (w & 1) * 32;
  f32x4 acc[2] = {};
  for (int kt = 0; kt < HD1 / 32; ++kt){
    {
      const int row = t >> 3, ch = (t & 7) * 4;
      *(uint2*)(&Al[row][ch]) = *(const uint2*)(A + (size_t)(m0 + row) * HD1 + kt * 32 + ch);
      const int kk = t >> 3, nn = (t & 7) * 8;
      short8 bv = *(const short8*)(Bb + (size_t)(kt * 32 + kk) * LATD + n0 + nn);
      #pragma unroll
      for (int i = 0; i < 8; ++i) Bl[nn + i][kk] = ((ushort*)&bv)[i];
    }
    __syncthreads();
    short8 a = *(const short8*)(&Al[wm + lr][lk * 8]);
    short8 b0 = *(const short8*)(&Bl[wn + lr][lk * 8]);
    short8 b1 = *(const short8*)(&Bl[wn + 16 + lr][lk * 8]);
    acc[0] = __builtin_amdgcn_mfma_f32_16x16x32_bf16(a, b0, acc[0], 0, 0, 0);
    acc[1] = __builtin_amdgcn_mfma_f32_16x16x32_bf16(a, b1, acc[1], 0, 0, 0);
    __syncthreads();
  }
  #pragma unroll
  for (int ni = 0; ni < 2; ++ni){
    const int row = m0 + wm + lk * 4;
    const int col = n0 + wn + ni * 16 + lr;
    #pragma unroll
    for (int r = 0; r < 4; ++r)
      Cb[(size_t)(row + r) * LATD + col] = f2bf(acc[ni][r]);
  }
}

// ---------------- mu/lv: single GEMM over Wcb (N=256), 64x64 tiles ----------------

__global__ __launch_bounds__(256) void gemm_mulv(const ushort* __restrict__ A,
    const ushort* __restrict__ Bb, const float* __restrict__ bmu,
    const float* __restrict__ blv, float* __restrict__ mu,
    ushort* __restrict__ mu_bf, float* __restrict__ lv)
{
  __shared__ ushort Al[64][40];
  __shared__ ushort Bl[64][40];
  const int t = threadIdx.x, w = t >> 6, l = t & 63, lr = l & 15, lk = l >> 4;
  const int n0 = blockIdx.x * 64, m0 = blockIdx.y * 64;
  const bool is_mu = n0 < LATD;
  const int wm = (w >> 1) * 32, wn = (w & 1) * 32;
  f32x4 acc[2][2] = {};
  for (int kt = 0; kt < LATD / 32; ++kt){
    {
      const int row = t >> 2, ch = t & 3;
      *(short8*)(&Al[row][ch * 8]) =
        *(const short8*)(A + (size_t)(m0 + row) * LATD + kt * 32 + ch * 8);
      const int kk = t >> 3, nn = (t & 7) * 8;
      short8 bv = *(const short8*)(Bb + (size_t)(kt * 32 + kk) * (2 * LATD) + n0 + nn);
      #pragma unroll
      for (int i = 0; i < 8; ++i) Bl[nn + i][kk] = ((ushort*)&bv)[i];
    }
    __syncthreads();
    short8 a0 = *(const short8*)(&Al[wm + lr][lk * 8]);
    short8 a1 = *(const short8*)(&Al[wm + 16 + lr][lk * 8]);
    short8 b0 = *(const short8*)(&Bl[wn + lr][lk * 8]);
    short8 b1 = *(const short8*)(&Bl[wn + 16 + lr][lk * 8]);
    acc[0][0] = __builtin_amdgcn_mfma_f32_16x16x32_bf16(a0, b0, acc[0][0], 0, 0, 0);
    acc[0][1] = __builtin_amdgcn_mfma_f32_16x16x32_bf16(a0, b1, acc[0][1], 0, 0, 0);
    acc[1][0] = __builtin_amdgcn_mfma_f32_16x16x32_bf16(a1, b0, acc[1][0], 0, 0, 0);
    acc[1][1] = __builtin_amdgcn_mfma_f32_16x16x32_bf16(a1, b1, acc[1][1], 0, 0, 0);
    __syncthreads();
  }
  #pragma unroll
  for (int mi = 0; mi < 2; ++mi){
    #pragma unroll
    for (int ni = 0; ni < 2; ++ni){
      const int row = m0 + wm + mi * 16 + lk * 4;
      const int col = n0 + wn + ni * 16 + lr;
      const float bb = is_mu ? bmu[col] : blv[col - LATD];
      #pragma unroll
      for (int r = 0; r < 4; ++r){
        const float v = acc[mi][ni][r] + bb;
        if (is_mu){
          mu[(size_t)(row + r) * LATD + col] = v;
          mu_bf[(size_t)(row + r) * LATD + col] = f2bf(v);
        } else {
          lv[(size_t)(row + r) * LATD + col - LATD] = v;
        }
      }
    }
  }
}

// ---------------- aggregation (bucket CSR, on-the-fly dis) ----------------

template<int F, bool RELU>
__global__ __launch_bounds__(256) void agg_kernel(const ushort* __restrict__ h,
    const float* __restrict__ bias, const int* __restrict__ cnt,
    const int* __restrict__ csr, ushort* __restrict__ out)
{
  constexpr int LPE = F / 8;
  constexpr int EPI = 64 / LPE;
  __shared__ int2 meta[4][64];
  const int w = threadIdx.x >> 6, l = threadIdx.x & 63;
  const int v = blockIdx.x * 4 + w;
  const int deg = min(cnt[v], CAP);
  const float dv = rsqrtf((float)(deg + 2));   // +2 self-loops (forward + gcn_norm)
  const int sub = l / LPE;
  const int eb = (l % LPE) * 8;
  float acc[8] = {0.f, 0.f, 0.f, 0.f, 0.f, 0.f, 0.f, 0.f};

  const int beg = v * CAP, end = beg + deg;
  for (int base = beg; base < end; base += 64){
    const int cc = min(64, end - base);
    int idx = 0; float nr = 0.f;
    if (base + l < end){
      idx = csr[base + l];
      nr = rsqrtf((float)(min(cnt[idx], CAP) + 2)) * dv;
    }
    int2 m; m.x = idx; m.y = __float_as_int(nr);
    meta[w][l] = m;
    asm volatile("s_waitcnt lgkmcnt(0)" ::: "memory");
    const int nIt = (cc + EPI - 1) / EPI;
    for (int it = 0; it < nIt; ++it){
      int2 mm = meta[w][it * EPI + sub];
      const float nrr = __int_as_float(mm.y);
      const uint4 r = *(const uint4*)(h + (size_t)mm.x * F + eb);
      acc[0] += nrr * bf2f(r.x & 0xffff); acc[1] += nrr * bf2f(r.x >> 16);
      acc[2] += nrr * bf2f(r.y & 0xffff); acc[3] += nrr * bf2f(r.y >> 16);
      acc[4] += nrr * bf2f(r.z & 0xffff); acc[5] += nrr * bf2f(r.z >> 16);
      acc[6] += nrr * bf2f(r.w & 0xffff); acc[7] += nrr * bf2f(r.w >> 16);
    }
    asm volatile("s_waitcnt lgkmcnt(0)" ::: "memory");
  }
  #pragma unroll
  for (int off = LPE; off < 64; off <<= 1){
    #pragma unroll
    for (int j = 0; j < 8; ++j) acc[j] += __shfl_xor(acc[j], off);
  }
  if (l < LPE){
    const float ss = 2.f * dv * dv;
    const uint4 r = *(const uint4*)(h + (size_t)v * F + eb);
    acc[0] += ss * bf2f(r.x & 0xffff); acc[1] += ss * bf2f(r.x >> 16);
    acc[2] += ss * bf2f(r.y & 0xffff); acc[3] += ss * bf2f(r.y >> 16);
    acc[4] += ss * bf2f(r.z & 0xffff); acc[5] += ss * bf2f(r.z >> 16);
    acc[6] += ss * bf2f(r.w & 0xffff); acc[7] += ss * bf2f(r.w >> 16);
    float4 b0 = *(const float4*)(bias + eb);
    float4 b1 = *(const float4*)(bias + eb + 4);
    acc[0] += b0.x; acc[1] += b0.y; acc[2] += b0.z; acc[3] += b0.w;
    acc[4] += b1.x; acc[5] += b1.y; acc[6] += b1.z; acc[7] += b1.w;
    if (RELU){
      #pragma unroll
      for (int j = 0; j < 8; ++j) acc[j] = fmaxf(acc[j], 0.f);
    }
    uint4 o;
    o.x = (uint)f2bf(acc[0]) | ((uint)f2bf(acc[1]) << 16);
    o.y = (uint)f2bf(acc[2]) | ((uint)f2bf(acc[3]) << 16);
    o.z = (uint)f2bf(acc[4]) | ((uint)f2bf(acc[5]) << 16);
    o.w = (uint)f2bf(acc[6]) | ((uint)f2bf(acc[7]) << 16);
    *(uint4*)(out + (size_t)v * F + eb) = o;
  }
}

// ---------------- adj = sigmoid(mu @ mu^T), 128x128 tiles, f32 out ----------------

__global__ __launch_bounds__(512) void gemm5_kernel(const ushort* __restrict__ mu,
                                                    float* __restrict__ adj)
{
  __shared__ char lds[65536];
  const int t = threadIdx.x;
  const int bj = blockIdx.x, bi = blockIdx.y;
  {
    const int row = t >> 2, ch = t & 3;
    const char* srcA = (const char*)(mu + (size_t)(bi * 128 + row) * LATD);
    const char* srcB = (const char*)(mu + (size_t)(bj * 128 + row) * LATD);
    char* dA = lds + row * 256;
    char* dB = lds + 32768 + row * 256;
    #pragma unroll
    for (int i = 0; i < 4; ++i){
      const int kb = ch * 64 + i * 16;
      const int sk = kb ^ ((row & 7) << 4);
      *(short8*)(dA + sk) = *(const short8*)(srcA + kb);
      *(short8*)(dB + sk) = *(const short8*)(srcB + kb);
    }
  }
  __syncthreads();
  const int wid = t >> 6, l = t & 63, lr = l & 15, lk = l >> 4;
  const int wm = (wid >> 2) * 64, wn = (wid & 3) * 32;
  f32x4 acc[4][2] = {};
  #pragma unroll
  for (int ks = 0; ks < 4; ++ks){
    short8 a[4], b[2];
    const int kb = ks * 64 + lk * 16;
    #pragma unroll
    for (int mi = 0; mi < 4; ++mi){
      const int r = wm + mi * 16 + lr;
      a[mi] = *(const short8*)(lds + r * 256 + (kb ^ ((r & 7) << 4)));
    }
    #pragma unroll
    for (int ni = 0; ni < 2; ++ni){
      const int r = wn + ni * 16 + lr;
      b[ni] = *(const short8*)(lds + 32768 + r * 256 + (kb ^ ((r & 7) << 4)));
    }
    #pragma unroll
    for (int mi = 0; mi < 4; ++mi)
      #pragma unroll
      for (int ni = 0; ni < 2; ++ni)
        acc[mi][ni] = __builtin_amdgcn_mfma_f32_16x16x32_bf16(a[mi], b[ni], acc[mi][ni], 0, 0, 0);
  }
  float* orow = adj + (size_t)(bi * 128 + wm + lk * 4) * NNODES + bj * 128 + wn + lr;
  #pragma unroll
  for (int mi = 0; mi < 4; ++mi){
    #pragma unroll
    for (int ni = 0; ni < 2; ++ni){
      #pragma unroll
      for (int r = 0; r < 4; ++r){
        const float x = acc[mi][ni][r];
        orow[(size_t)(mi * 16 + r) * NNODES + ni * 16] = 1.f / (1.f + __expf(-x));
      }
    }
  }
}

// ---------------- launch ----------------

extern "C" void kernel_launch(void* const* d_in, const int* in_sizes, int n_in,
                              void* d_out, int out_size, void* d_ws, size_t ws_size,
                              hipStream_t stream)
{
  const float* x    = (const float*)d_in[0];
  const int*   ei   = (const int*)d_in[1];
  const float* W1   = (const float*)d_in[2];
  const float* b1   = (const float*)d_in[3];
  const float* W2   = (const float*)d_in[4];
  const float* b2   = (const float*)d_in[5];
  const float* Wmu  = (const float*)d_in[6];
  const float* bmu  = (const float*)d_in[7];
  const float* Wlv  = (const float*)d_in[8];
  const float* blv  = (const float*)d_in[9];
  const int E = in_sizes[1] / 2;
  const int* erow = ei;
  const int* ecol = ei + E;

  char* ws = (char*)d_ws;
  int*    cnt   = (int*)(ws);                  // 32KB
  ushort* W1b   = (ushort*)(ws + 65536);       // 256KB
  ushort* W2b   = (ushort*)(ws + 327680);      // 64KB
  ushort* Wcb   = (ushort*)(ws + 393216);      // 64KB (128x256)
  int*    csr   = (int*)(ws + 1048576);        // 4MB buckets
  ushort* h1    = (ushort*)(ws + 8388608);     // 4MB
  ushort* z1    = (ushort*)(ws + 12582912);    // 4MB
  ushort* h2    = (ushort*)(ws + 16777216);    // 2MB
  ushort* z2    = (ushort*)(ws + 18874368);    // 2MB
  ushort* mu_bf = (ushort*)(ws + 20971520);    // 2MB

  float* adj = (float*)d_out;
  float* mu  = adj + (size_t)NNODES * NNODES;
  float* lv  = mu + (size_t)NNODES * LATD;

  const int nbF = (E + 255) / 256;

  // zero cnt + weight bf16 conversion (replaces memset node)
  k_init<<<128, 256, 0, stream>>>(W1, W2, Wmu, Wlv, cnt, W1b, W2b, Wcb);
  // fused: bucket CSR fill + gemm1 (h1 = bf16(x) @ W1b)
  k_fill_gemm1<<<nbF + 4 * (NNODES / 64), 256, 0, stream>>>(
      erow, ecol, E, nbF, cnt, csr, x, W1b, h1);
  // z1 = relu(agg(h1) + b1)
  agg_kernel<HD1, true><<<NNODES / 4, 256, 0, stream>>>(h1, b1, cnt, csr, z1);
  // h2 = z1 @ W2b
  gemm2_kernel<<<dim3(LATD / 64, NNODES / 32), 256, 0, stream>>>(z1, W2b, h2);
  // z2 = agg(h2) + b2
  agg_kernel<LATD, false><<<NNODES / 4, 256, 0, stream>>>(h2, b2, cnt, csr, z2);
  // mu (f32 + bf16) / logvar (f32), single GEMM over [Wmu|Wlv]
  gemm_mulv<<<dim3(2 * LATD / 64, NNODES / 64), 256, 0, stream>>>(
      z2, Wcb, bmu, blv, mu, mu_bf, lv);
  // adj = sigmoid(mu @ mu^T)
  gemm5_kernel<<<dim3(NNODES / 128, NNODES / 128), 512, 0, stream>>>(mu_bf, adj);
}